// Round 12
// baseline (187.208 us; speedup 1.0000x reference)
//
#include <hip/hip_runtime.h>
#include <hip/hip_bf16.h>
#include <math.h>

#define D_MODEL 1024
#define NH 16
#define DK 64
#define SEQ 2048
#define BATCH 2
#define MTOT (BATCH * SEQ)

typedef unsigned short u16;
typedef unsigned int u32;
typedef short bf16x8 __attribute__((ext_vector_type(8)));   // 8 bf16 = 4 VGPR (K=32 A/B frag)
typedef short bf16x4 __attribute__((ext_vector_type(4)));   // 4 bf16 = 2 VGPR (K=16 A/B frag)
typedef float f32x4 __attribute__((ext_vector_type(4)));    // C/D frag

// log2-domain constants: softmax computes exp2((S/sqrt(dk))*log2e + mask)
static constexpr float NEGV2 = -1e8f * 1.44269504089f;   // mask addend (log2 domain)
static constexpr float SCL2  = 0.125f * 1.44269504089f;  // (1/sqrt(64)) * log2e

__device__ __forceinline__ u16 f2bf(float f) {
    union { float f; u32 u; } v; v.f = f;
    u32 r = v.u + 0x7FFFu + ((v.u >> 16) & 1u);  // RNE
    return (u16)(r >> 16);
}

__device__ __forceinline__ float fexp2(float x) {
#if __has_builtin(__builtin_amdgcn_exp2f)
    return __builtin_amdgcn_exp2f(x);   // v_exp_f32 (2^x) directly
#else
    return __expf(x * 0.69314718056f);
#endif
}

// pack 2 f32 -> u32 of 2 bf16 (RNE) via the HIP-provided conversion
__device__ __forceinline__ u32 pack2(float lo, float hi) {
    union { __hip_bfloat162 h; u32 u; } cv;
    cv.h = __float22bfloat162_rn(float2{lo, hi});
    return cv.u;
}

__device__ __forceinline__ f32x4 mfma16(bf16x4 a, bf16x4 b, f32x4 c) {
#if __has_builtin(__builtin_amdgcn_mfma_f32_16x16x16_bf16)
    return __builtin_amdgcn_mfma_f32_16x16x16_bf16(a, b, c, 0, 0, 0);
#else
    return __builtin_amdgcn_mfma_f32_16x16x16bf16_1k(a, b, c, 0, 0, 0);
#endif
}

__device__ __forceinline__ void stage16(const u16* g, u16* lds_per_lane) {
#if __has_builtin(__builtin_amdgcn_global_load_lds)
    __builtin_amdgcn_global_load_lds((const __attribute__((address_space(1))) u32*)g,
                                     (__attribute__((address_space(3))) u32*)lds_per_lane,
                                     16, 0, 0);
#else
    *(uint4*)lds_per_lane = *(const uint4*)g;
#endif
}

// ------- fp32 -> bf16 conversion of X and Wq|Wk|Wv; mask -> log2 addends ----
__global__ __launch_bounds__(256) void convert_bf16(
    const float* __restrict__ X, const float* __restrict__ Wq,
    const float* __restrict__ Wk, const float* __restrict__ Wv,
    const int* __restrict__ mask,
    u16* __restrict__ Xb, u16* __restrict__ Wb, float* __restrict__ madsg)
{
    const int NX = MTOT * D_MODEL / 4;
    const int NW = D_MODEL * D_MODEL / 4;
    const int NM = MTOT / 4;
    int i = blockIdx.x * 256 + threadIdx.x;
    if (i >= NX + 3 * NW + NM) return;
    if (i >= NX + 3 * NW) {  // mask -> float addend table (log2 domain)
        int j = i - NX - 3 * NW;
        int4 mi = ((const int4*)mask)[j];
        float4 o;
        o.x = mi.x ? NEGV2 : 0.0f; o.y = mi.y ? NEGV2 : 0.0f;
        o.z = mi.z ? NEGV2 : 0.0f; o.w = mi.w ? NEGV2 : 0.0f;
        ((float4*)madsg)[j] = o;
        return;
    }
    float4 v; u16* dst;
    if (i < NX)             { v = ((const float4*)X )[i];            dst = Xb + (size_t)i * 4; }
    else if (i < NX + NW)   { v = ((const float4*)Wq)[i - NX];       dst = Wb + (size_t)(i - NX) * 4; }
    else if (i < NX + 2*NW) { v = ((const float4*)Wk)[i - NX - NW];  dst = Wb + (size_t)NW * 4 + (size_t)(i - NX - NW) * 4; }
    else                    { v = ((const float4*)Wv)[i - NX - 2*NW];dst = Wb + (size_t)NW * 8 + (size_t)(i - NX - 2*NW) * 4; }
    ushort4 o;
    o.x = f2bf(v.x); o.y = f2bf(v.y); o.z = f2bf(v.z); o.w = f2bf(v.w);
    *(ushort4*)dst = o;
}

// ---------------- QKV projection: MFMA GEMM, y = Xb @ Wb^T + bias ----------
// XCD-chunked block swizzle (bijective since 768 % 8 == 0).
__global__ __launch_bounds__(256, 2) void proj_mfma(
    const u16* __restrict__ Xb, const u16* __restrict__ Wb,
    const float* __restrict__ bq, const float* __restrict__ bk, const float* __restrict__ bv,
    u16* __restrict__ Qb, u16* __restrict__ Kb, u16* __restrict__ Vb)
{
    __shared__ u16 As[128 * 32];
    __shared__ u16 Bs[128 * 32];

    const int id = blockIdx.x + 32 * blockIdx.y + 256 * blockIdx.z;  // [0,768)
    const int swz = (id & 7) * 96 + (id >> 3);
    const int xm = swz & 31;          // m-tile
    const int yn = (swz >> 5) & 7;    // n-tile
    const int zi = swz >> 8;          // which

    const u16* __restrict__ W = Wb + (size_t)zi * D_MODEL * D_MODEL;
    const float* __restrict__ bias = zi == 0 ? bq : (zi == 1 ? bk : bv);
    u16* __restrict__ Out = zi == 0 ? Qb : (zi == 1 ? Kb : Vb);

    const int m0 = xm * 128, n0 = yn * 128;
    const int tid = threadIdx.x, lane = tid & 63, w = tid >> 6;
    const int quad = lane >> 4, l15 = lane & 15;
    const int wr = w >> 1, wc = w & 1;

    f32x4 acc[4][4];
#pragma unroll
    for (int i = 0; i < 4; i++)
#pragma unroll
        for (int j = 0; j < 4; j++) acc[i][j] = (f32x4)0.0f;

    const int srow = 32 * w + (lane >> 2);
    const int scol = (lane & 3) * 8;

    for (int k0 = 0; k0 < D_MODEL; k0 += 32) {
#pragma unroll
        for (int t = 0; t < 2; t++) {
            stage16(Xb + (size_t)(m0 + srow + 16 * t) * D_MODEL + k0 + scol,
                    &As[(32 * w + 16 * t) * 32 + lane * 8]);
            stage16(W + (size_t)(n0 + srow + 16 * t) * D_MODEL + k0 + scol,
                    &Bs[(32 * w + 16 * t) * 32 + lane * 8]);
        }
        __syncthreads();
        bf16x8 af[4], bfr[4];
#pragma unroll
        for (int i = 0; i < 4; i++)
            af[i] = *(const bf16x8*)&As[(wr * 64 + i * 16 + l15) * 32 + quad * 8];
#pragma unroll
        for (int j = 0; j < 4; j++)
            bfr[j] = *(const bf16x8*)&Bs[(wc * 64 + j * 16 + l15) * 32 + quad * 8];
#pragma unroll
        for (int i = 0; i < 4; i++)
#pragma unroll
            for (int j = 0; j < 4; j++)
                acc[i][j] = __builtin_amdgcn_mfma_f32_16x16x32_bf16(af[i], bfr[j], acc[i][j], 0, 0, 0);
        __syncthreads();
    }

    float bj[4];
#pragma unroll
    for (int j = 0; j < 4; j++) bj[j] = bias[n0 + wc * 64 + j * 16 + l15];
#pragma unroll
    for (int i = 0; i < 4; i++) {
#pragma unroll
        for (int j = 0; j < 4; j++) {
#pragma unroll
            for (int r = 0; r < 4; r++) {
                int m = m0 + wr * 64 + i * 16 + quad * 4 + r;
                int n = n0 + wc * 64 + j * 16 + l15;
                int b = m >> 11, s = m & (SEQ - 1);
                int h = n >> 6, d = n & 63;
                Out[(((size_t)b * NH + h) * SEQ + s) * DK + d] = f2bf(acc[i][j][r] + bj[j]);
            }
        }
    }
}

// -------- MFMA flash attention, cross-block K-split (R5 core intact) ------
// Each block runs the EXACT round-5 double-buffered schedule over HALF the
// keys (grp 0: [0,1024), grp 1: [1024,2048)) -- zero per-thread work
// amplification, 1 barrier/chunk, 16 chunks. No-max softmax => partials are
// additive: block writes unnormalized O (fp32) + denominator; combine_norm
// sums the 2 partials and normalizes. Grid 1024 -> 4 blocks/CU (LDS 36.9KB,
// mask addends read from global table). XCD-chunked swizzle keeps each
// (b,h)'s K/V in one XCD's L2.
__global__ __launch_bounds__(256, 4) void attn_mfma(
    const u16* __restrict__ Qg, const u16* __restrict__ Kg, const u16* __restrict__ Vg,
    const float* __restrict__ madsg, float* __restrict__ Pbuf, float* __restrict__ Lbuf)
{
    constexpr int PADK = 72, PADV = 72;
    constexpr int HK = SEQ / 2;        // keys per block
    constexpr int NT = HK / 64;        // 16 chunks
    __shared__ u16 Ks[2][64 * PADK];   // [key][dk], straight
    __shared__ u16 Vt[2][64 * PADV];   // [dk][key], transposed

    // XCD-chunked swizzle over 1024 blocks: XCD = id0 % 8 owns 128
    // consecutive logical ids = 4 (b,h) panels x 16 q-tiles x 2 key-halves.
    const int id0 = blockIdx.x;                     // [0,1024)
    const int nid = (id0 & 7) * 128 + (id0 >> 3);
    const int grp = nid & 1;                        // key half
    const int qt0 = (nid >> 1) & 15, h = (nid >> 5) & 15, b = nid >> 9;

    const int tid = threadIdx.x, lane = tid & 63, w = tid >> 6;
    const int quad = lane >> 4, l15 = lane & 15;
    const size_t bh = (size_t)b * NH + h;
    const u16* __restrict__ Qp = Qg + (bh * SEQ + qt0 * 128) * DK;
    const u16* __restrict__ Kp = Kg + (bh * SEQ + (size_t)grp * HK) * DK;
    const u16* __restrict__ Vp = Vg + (bh * SEQ + (size_t)grp * HK) * DK;
    const float* __restrict__ mp = madsg + b * SEQ + grp * HK;

    // persistent Q fragments (B operand): B[k=dk][n=q], n=l15, k=quad*8+j
    const int q0 = w * 32;
    bf16x8 qf[2][2];
#pragma unroll
    for (int qt = 0; qt < 2; qt++)
#pragma unroll
        for (int half = 0; half < 2; half++)
            qf[qt][half] = *(const bf16x8*)(Qp + (size_t)(q0 + qt * 16 + l15) * DK + half * 32 + quad * 8);

    // staging index maps (identical to round-5)
    const int skey = tid & 63, sdk = (tid >> 6) * 16;       // K loader
    const int vkp2 = (tid & 31) * 2, vd0 = (tid >> 5) * 8;  // V loader (2 keys x 8 dk)

    // stage chunk 0 into buffer 0
    {
        const u16* kr = Kp + (size_t)skey * DK + sdk;
        bf16x8 k0 = *(const bf16x8*)kr, k1 = *(const bf16x8*)(kr + 8);
        u16* kd = &Ks[0][skey * PADK + sdk];
        *(bf16x8*)kd = k0; *(bf16x8*)(kd + 8) = k1;
        const u16* vr = Vp + (size_t)vkp2 * DK + vd0;
        bf16x8 v0 = *(const bf16x8*)vr, v1 = *(const bf16x8*)(vr + DK);
#pragma unroll
        for (int i = 0; i < 8; i++)
            *(u32*)&Vt[0][(vd0 + i) * PADV + vkp2] = (u32)(u16)v0[i] | ((u32)(u16)v1[i] << 16);
    }
    __syncthreads();

    f32x4 O[4][2];    // O^T partial: [d-tile][q-tile], d=quad*4+r, q=l15
    f32x4 sacc[2];    // per-lane partial denominators
#pragma unroll
    for (int dt = 0; dt < 4; dt++)
#pragma unroll
        for (int qt = 0; qt < 2; qt++) O[dt][qt] = (f32x4)0.0f;
    sacc[0] = (f32x4)0.0f; sacc[1] = (f32x4)0.0f;

    for (int kt = 0; kt < NT; kt++) {
        const int bb = kt & 1;
        // prefetch next chunk (global -> regs)
        bf16x8 nk0, nk1, nv0, nv1;
        if (kt < NT - 1) {
            const u16* kr = Kp + (size_t)((kt + 1) * 64 + skey) * DK + sdk;
            nk0 = *(const bf16x8*)kr; nk1 = *(const bf16x8*)(kr + 8);
            const u16* vr = Vp + (size_t)((kt + 1) * 64 + vkp2) * DK + vd0;
            nv0 = *(const bf16x8*)vr; nv1 = *(const bf16x8*)(vr + DK);
        }

        // --- S^T = K Q^T: [4 key-tiles][2 q-tiles], key=quad*4+r, q=l15 ---
        f32x4 St[4][2];
#pragma unroll
        for (int ktl = 0; ktl < 4; ktl++) {
            bf16x8 kf0 = *(const bf16x8*)&Ks[bb][(ktl * 16 + l15) * PADK + quad * 8];
            bf16x8 kf1 = *(const bf16x8*)&Ks[bb][(ktl * 16 + l15) * PADK + 32 + quad * 8];
#pragma unroll
            for (int qt = 0; qt < 2; qt++) {
                f32x4 acc = (f32x4)0.0f;
                acc = __builtin_amdgcn_mfma_f32_16x16x32_bf16(kf0, qf[qt][0], acc, 0, 0, 0);
                acc = __builtin_amdgcn_mfma_f32_16x16x32_bf16(kf1, qf[qt][1], acc, 0, 0, 0);
                St[ktl][qt] = acc;
            }
        }

        // --- scale+mask (log2 domain, one fma) then exp2 + partial sums ---
#pragma unroll
        for (int ktl = 0; ktl < 4; ktl++) {
            f32x4 ma = *(const f32x4*)&mp[kt * 64 + ktl * 16 + quad * 4];
#pragma unroll
            for (int qt = 0; qt < 2; qt++)
#pragma unroll
                for (int r = 0; r < 4; r++) {
                    float p = fexp2(St[ktl][qt][r] * SCL2 + ma[r]);
                    St[ktl][qt][r] = p;
                    sacc[qt][r] += p;
                }
        }

        // --- pack P^T to bf16 (already in B-frag layout for 16x16x16) ---
        bf16x4 pf[4][2];
#pragma unroll
        for (int ktl = 0; ktl < 4; ktl++)
#pragma unroll
            for (int qt = 0; qt < 2; qt++) {
                union { u32 u[2]; bf16x4 v; } pu;
                pu.u[0] = pack2(St[ktl][qt][0], St[ktl][qt][1]);
                pu.u[1] = pack2(St[ktl][qt][2], St[ktl][qt][3]);
                pf[ktl][qt] = pu.v;
            }

        // --- O^T += V^T P^T (16x16x16; A=V^T b64 reads from Vt) ---
#pragma unroll
        for (int ktl = 0; ktl < 4; ktl++)
#pragma unroll
            for (int dt = 0; dt < 4; dt++) {
                bf16x4 vf = *(const bf16x4*)&Vt[bb][(dt * 16 + l15) * PADV + ktl * 16 + quad * 4];
#pragma unroll
                for (int qt = 0; qt < 2; qt++)
                    O[dt][qt] = mfma16(vf, pf[ktl][qt], O[dt][qt]);
            }

        // --- write prefetched chunk into the other buffer ---
        if (kt < NT - 1) {
            u16* kd = &Ks[bb ^ 1][skey * PADK + sdk];
            *(bf16x8*)kd = nk0; *(bf16x8*)(kd + 8) = nk1;
#pragma unroll
            for (int i = 0; i < 8; i++)
                *(u32*)&Vt[bb ^ 1][(vd0 + i) * PADV + vkp2] = (u32)(u16)nv0[i] | ((u32)(u16)nv1[i] << 16);
        }
        __syncthreads();
    }

    // --- epilogue: write UNNORMALIZED partial O and denominator ---
#pragma unroll
    for (int qt = 0; qt < 2; qt++) {
        float sum = (sacc[qt][0] + sacc[qt][1]) + (sacc[qt][2] + sacc[qt][3]);
        sum += __shfl_xor(sum, 16);
        sum += __shfl_xor(sum, 32);   // replicated across quads
        int q = qt0 * 128 + q0 + qt * 16 + l15;
        if (quad == 0)
            Lbuf[(((size_t)grp * BATCH + b) * NH + h) * SEQ + q] = sum;
        float* op = Pbuf + (((size_t)grp * BATCH + b) * SEQ + q) * D_MODEL + h * DK;
#pragma unroll
        for (int dt = 0; dt < 4; dt++)
#pragma unroll
            for (int r = 0; r < 4; r++)
                op[dt * 16 + quad * 4 + r] = O[dt][qt][r];
    }
}

// -------- combine the two key-half partials and normalize -----------------
__global__ __launch_bounds__(256) void combine_norm(
    const float* __restrict__ P, const float* __restrict__ L, float* __restrict__ out)
{
    const int total = MTOT * D_MODEL / 4;   // float4 count per half
    int i = blockIdx.x * 256 + threadIdx.x;
    if (i >= total) return;
    int e = i * 4;
    int b = e >> 21;                 // SEQ*D_MODEL = 2^21 elements per batch
    int s = (e >> 10) & (SEQ - 1);
    int h = (e & (D_MODEL - 1)) >> 6;
    size_t li = ((size_t)b * NH + h) * SEQ + s;
    float inv = 1.0f / (L[li] + L[(size_t)BATCH * NH * SEQ + li]);
    float4 p0 = ((const float4*)P)[i];
    float4 p1 = ((const float4*)P)[i + total];
    float4 o;
    o.x = (p0.x + p1.x) * inv;
    o.y = (p0.y + p1.y) * inv;
    o.z = (p0.z + p1.z) * inv;
    o.w = (p0.w + p1.w) * inv;
    ((float4*)out)[i] = o;
}

extern "C" void kernel_launch(void* const* d_in, const int* in_sizes, int n_in,
                              void* d_out, int out_size, void* d_ws, size_t ws_size,
                              hipStream_t stream)
{
    const float* X  = (const float*)d_in[0];
    const int* mask = (const int*)d_in[1];
    const float* Wq = (const float*)d_in[2];
    const float* bq = (const float*)d_in[3];
    const float* Wk = (const float*)d_in[4];
    const float* bk = (const float*)d_in[5];
    const float* Wv = (const float*)d_in[6];
    const float* bv = (const float*)d_in[7];
    float* out = (float*)d_out;

    u16* Xb = (u16*)d_ws;
    u16* Wb = Xb + (size_t)MTOT * D_MODEL;
    u16* Qb = Wb + (size_t)3 * D_MODEL * D_MODEL;
    u16* Kb = Qb + (size_t)BATCH * NH * SEQ * DK;
    u16* Vb = Kb + (size_t)BATCH * NH * SEQ * DK;
    float* madsg = (float*)(Vb + (size_t)BATCH * NH * SEQ * DK);
    float* Pbuf = madsg + MTOT;                       // 2 x MTOT x D_MODEL f32
    float* Lbuf = Pbuf + (size_t)2 * MTOT * D_MODEL;  // 2 x BATCH x NH x SEQ f32

    const int ncvt = (MTOT * D_MODEL + 3 * D_MODEL * D_MODEL + MTOT) / 4;
    convert_bf16<<<(ncvt + 255) / 256, 256, 0, stream>>>(X, Wq, Wk, Wv, mask, Xb, Wb, madsg);
    proj_mfma<<<dim3(MTOT / 128, D_MODEL / 128, 3), 256, 0, stream>>>(Xb, Wb, bq, bk, bv, Qb, Kb, Vb);
    attn_mfma<<<dim3(SEQ / 128 * NH * BATCH * 2), 256, 0, stream>>>(Qb, Kb, Vb, madsg, Pbuf, Lbuf);
    combine_norm<<<(MTOT * D_MODEL / 4 + 255) / 256, 256, 0, stream>>>(Pbuf, Lbuf, out);
}

// Round 13
// 173.391 us; speedup vs baseline: 1.0797x; 1.0797x over previous
//
#include <hip/hip_runtime.h>
#include <hip/hip_bf16.h>
#include <math.h>

#define D_MODEL 1024
#define NH 16
#define DK 64
#define SEQ 2048
#define BATCH 2
#define MTOT (BATCH * SEQ)

typedef unsigned short u16;
typedef unsigned int u32;
typedef short bf16x8 __attribute__((ext_vector_type(8)));   // 8 bf16 = 4 VGPR (K=32 A/B frag)
typedef short bf16x4 __attribute__((ext_vector_type(4)));   // 4 bf16 = 2 VGPR (K=16 A/B frag)
typedef float f32x4 __attribute__((ext_vector_type(4)));    // C/D frag

// log2-domain constants: softmax computes exp2((S/sqrt(dk))*log2e + mask)
// so v_exp_f32 (2^x) applies directly with no per-element multiply.
static constexpr float NEGV2 = -1e8f * 1.44269504089f;   // mask addend (log2 domain)
static constexpr float SCL2  = 0.125f * 1.44269504089f;  // (1/sqrt(64)) * log2e

__device__ __forceinline__ u16 f2bf(float f) {
    union { float f; u32 u; } v; v.f = f;
    u32 r = v.u + 0x7FFFu + ((v.u >> 16) & 1u);  // RNE
    return (u16)(r >> 16);
}

__device__ __forceinline__ float fexp2(float x) {
#if __has_builtin(__builtin_amdgcn_exp2f)
    return __builtin_amdgcn_exp2f(x);   // v_exp_f32 (2^x) directly, no mul
#else
    return __expf(x * 0.69314718056f);
#endif
}

// pack 2 f32 -> u32 of 2 bf16 (RNE) via the HIP-provided conversion; the
// compiler may lower this to v_cvt_pk_bf16_f32. Semantics guaranteed.
__device__ __forceinline__ u32 pack2(float lo, float hi) {
    union { __hip_bfloat162 h; u32 u; } cv;
    cv.h = __float22bfloat162_rn(float2{lo, hi});
    return cv.u;
}

__device__ __forceinline__ f32x4 mfma16(bf16x4 a, bf16x4 b, f32x4 c) {
#if __has_builtin(__builtin_amdgcn_mfma_f32_16x16x16_bf16)
    return __builtin_amdgcn_mfma_f32_16x16x16_bf16(a, b, c, 0, 0, 0);
#else
    return __builtin_amdgcn_mfma_f32_16x16x16bf16_1k(a, b, c, 0, 0, 0);
#endif
}

__device__ __forceinline__ void stage16(const u16* g, u16* lds_per_lane) {
#if __has_builtin(__builtin_amdgcn_global_load_lds)
    __builtin_amdgcn_global_load_lds((const __attribute__((address_space(1))) u32*)g,
                                     (__attribute__((address_space(3))) u32*)lds_per_lane,
                                     16, 0, 0);
#else
    *(uint4*)lds_per_lane = *(const uint4*)g;
#endif
}

// ---------------- fp32 -> bf16 conversion of X and Wq|Wk|Wv ----------------
__global__ __launch_bounds__(256) void convert_bf16(
    const float* __restrict__ X, const float* __restrict__ Wq,
    const float* __restrict__ Wk, const float* __restrict__ Wv,
    u16* __restrict__ Xb, u16* __restrict__ Wb)
{
    const int NX = MTOT * D_MODEL / 4;
    const int NW = D_MODEL * D_MODEL / 4;
    int i = blockIdx.x * 256 + threadIdx.x;
    if (i >= NX + 3 * NW) return;
    float4 v; u16* dst;
    if (i < NX)             { v = ((const float4*)X )[i];            dst = Xb + (size_t)i * 4; }
    else if (i < NX + NW)   { v = ((const float4*)Wq)[i - NX];       dst = Wb + (size_t)(i - NX) * 4; }
    else if (i < NX + 2*NW) { v = ((const float4*)Wk)[i - NX - NW];  dst = Wb + (size_t)NW * 4 + (size_t)(i - NX - NW) * 4; }
    else                    { v = ((const float4*)Wv)[i - NX - 2*NW];dst = Wb + (size_t)NW * 8 + (size_t)(i - NX - 2*NW) * 4; }
    ushort4 o;
    o.x = f2bf(v.x); o.y = f2bf(v.y); o.z = f2bf(v.z); o.w = f2bf(v.w);
    *(ushort4*)dst = o;
}

// ---------------- QKV projection: MFMA GEMM, y = Xb @ Wb^T + bias ----------
__global__ __launch_bounds__(256, 2) void proj_mfma(
    const u16* __restrict__ Xb, const u16* __restrict__ Wb,
    const float* __restrict__ bq, const float* __restrict__ bk, const float* __restrict__ bv,
    u16* __restrict__ Qb, u16* __restrict__ Kb, u16* __restrict__ Vb)
{
    __shared__ u16 As[128 * 32];
    __shared__ u16 Bs[128 * 32];

    const int which = blockIdx.z;
    const u16* __restrict__ W = Wb + (size_t)which * D_MODEL * D_MODEL;
    const float* __restrict__ bias = which == 0 ? bq : (which == 1 ? bk : bv);
    u16* __restrict__ Out = which == 0 ? Qb : (which == 1 ? Kb : Vb);

    const int m0 = blockIdx.x * 128, n0 = blockIdx.y * 128;
    const int tid = threadIdx.x, lane = tid & 63, w = tid >> 6;
    const int quad = lane >> 4, l15 = lane & 15;
    const int wr = w >> 1, wc = w & 1;

    f32x4 acc[4][4];
#pragma unroll
    for (int i = 0; i < 4; i++)
#pragma unroll
        for (int j = 0; j < 4; j++) acc[i][j] = (f32x4)0.0f;

    const int srow = 32 * w + (lane >> 2);
    const int scol = (lane & 3) * 8;

    for (int k0 = 0; k0 < D_MODEL; k0 += 32) {
#pragma unroll
        for (int t = 0; t < 2; t++) {
            stage16(Xb + (size_t)(m0 + srow + 16 * t) * D_MODEL + k0 + scol,
                    &As[(32 * w + 16 * t) * 32 + lane * 8]);
            stage16(W + (size_t)(n0 + srow + 16 * t) * D_MODEL + k0 + scol,
                    &Bs[(32 * w + 16 * t) * 32 + lane * 8]);
        }
        __syncthreads();
        bf16x8 af[4], bfr[4];
#pragma unroll
        for (int i = 0; i < 4; i++)
            af[i] = *(const bf16x8*)&As[(wr * 64 + i * 16 + l15) * 32 + quad * 8];
#pragma unroll
        for (int j = 0; j < 4; j++)
            bfr[j] = *(const bf16x8*)&Bs[(wc * 64 + j * 16 + l15) * 32 + quad * 8];
#pragma unroll
        for (int i = 0; i < 4; i++)
#pragma unroll
            for (int j = 0; j < 4; j++)
                acc[i][j] = __builtin_amdgcn_mfma_f32_16x16x32_bf16(af[i], bfr[j], acc[i][j], 0, 0, 0);
        __syncthreads();
    }

    float bj[4];
#pragma unroll
    for (int j = 0; j < 4; j++) bj[j] = bias[n0 + wc * 64 + j * 16 + l15];
#pragma unroll
    for (int i = 0; i < 4; i++) {
#pragma unroll
        for (int j = 0; j < 4; j++) {
#pragma unroll
            for (int r = 0; r < 4; r++) {
                int m = m0 + wr * 64 + i * 16 + quad * 4 + r;
                int n = n0 + wc * 64 + j * 16 + l15;
                int b = m >> 11, s = m & (SEQ - 1);
                int h = n >> 6, d = n & 63;
                Out[(((size_t)b * NH + h) * SEQ + s) * DK + d] = f2bf(acc[i][j][r] + bj[j]);
            }
        }
    }
}

// ---------------- MFMA flash attention (transposed-score scheme) ----------
// S^T = K Q^T via 16x16x32; P^T lands in C-layout == B-frag of 16x16x16
// => O^T = V^T P^T with zero LDS round-trip for P. K/V double-buffered,
// 1 barrier/chunk. Geometry: 256 threads = 4 waves x 32 queries.
// Softmax WITHOUT max tracking: scores bounded (|S|*SCL2 << 128, the
// v_exp_f32 overflow point); masked keys give exp2(-1.4e8) = 0. Per-lane
// partial sums in registers; one cross-quad reduction in the epilogue.
// [Session-verified optimum: 66.2 us attn / 175.9 us total. Structural
// variants measured and rejected: 8x16-wave split (R4, LDS-read 2x),
// 2-wave blocks (R7, staging 2x), in-block K-split (R8), K-from-global
// (R9, scattered loads), setprio (R10, -2us in lockstep), cross-block
// K-split (R12, throughput invariant to occupancy).]
__global__ __launch_bounds__(256, 2) void attn_mfma(
    const u16* __restrict__ Qg, const u16* __restrict__ Kg, const u16* __restrict__ Vg,
    const int* __restrict__ mask, float* __restrict__ out)
{
    constexpr int PADK = 72, PADV = 72;
    __shared__ u16 Ks[2][64 * PADK];   // [key][dk], straight
    __shared__ u16 Vt[2][64 * PADV];   // [dk][key], transposed
    __shared__ float mads[SEQ];        // per-key mask addend (0 or NEGV2)

    const int qt0 = blockIdx.x, h = blockIdx.y, b = blockIdx.z;
    const int tid = threadIdx.x, lane = tid & 63, w = tid >> 6;
    const int quad = lane >> 4, l15 = lane & 15;
    const size_t bh = (size_t)b * NH + h;
    const u16* __restrict__ Qp = Qg + (bh * SEQ + qt0 * 128) * DK;
    const u16* __restrict__ Kp = Kg + bh * SEQ * DK;
    const u16* __restrict__ Vp = Vg + bh * SEQ * DK;
    const int* __restrict__ mp = mask + b * SEQ;

    // mask addend table (log2 domain)
    for (int i = tid; i < SEQ; i += 256) mads[i] = mp[i] ? NEGV2 : 0.0f;

    // persistent Q fragments (B operand): B[k=dk][n=q], n=l15, k=quad*8+j
    const int q0 = w * 32;
    bf16x8 qf[2][2];
#pragma unroll
    for (int qt = 0; qt < 2; qt++)
#pragma unroll
        for (int half = 0; half < 2; half++)
            qf[qt][half] = *(const bf16x8*)(Qp + (size_t)(q0 + qt * 16 + l15) * DK + half * 32 + quad * 8);

    // staging index maps
    const int skey = tid & 63, sdk = (tid >> 6) * 16;       // K loader
    const int vkp2 = (tid & 31) * 2, vd0 = (tid >> 5) * 8;  // V loader (2 keys x 8 dk)

    // stage chunk 0 into buffer 0
    {
        const u16* kr = Kp + (size_t)skey * DK + sdk;
        bf16x8 k0 = *(const bf16x8*)kr, k1 = *(const bf16x8*)(kr + 8);
        u16* kd = &Ks[0][skey * PADK + sdk];
        *(bf16x8*)kd = k0; *(bf16x8*)(kd + 8) = k1;
        const u16* vr = Vp + (size_t)vkp2 * DK + vd0;
        bf16x8 v0 = *(const bf16x8*)vr, v1 = *(const bf16x8*)(vr + DK);
#pragma unroll
        for (int i = 0; i < 8; i++)
            *(u32*)&Vt[0][(vd0 + i) * PADV + vkp2] = (u32)(u16)v0[i] | ((u32)(u16)v1[i] << 16);
    }
    __syncthreads();

    f32x4 O[4][2];    // O^T: [d-tile][q-tile], d=quad*4+r, q=l15
    f32x4 sacc[2];    // per-lane partial softmax denominators (per q-tile)
#pragma unroll
    for (int dt = 0; dt < 4; dt++)
#pragma unroll
        for (int qt = 0; qt < 2; qt++) O[dt][qt] = (f32x4)0.0f;
    sacc[0] = (f32x4)0.0f; sacc[1] = (f32x4)0.0f;

    for (int kt = 0; kt < SEQ / 64; kt++) {
        const int bb = kt & 1;
        // prefetch next chunk (global -> regs)
        bf16x8 nk0, nk1, nv0, nv1;
        if (kt < SEQ / 64 - 1) {
            const u16* kr = Kp + (size_t)((kt + 1) * 64 + skey) * DK + sdk;
            nk0 = *(const bf16x8*)kr; nk1 = *(const bf16x8*)(kr + 8);
            const u16* vr = Vp + (size_t)((kt + 1) * 64 + vkp2) * DK + vd0;
            nv0 = *(const bf16x8*)vr; nv1 = *(const bf16x8*)(vr + DK);
        }

        // --- S^T = K Q^T: [4 key-tiles][2 q-tiles], key=quad*4+r, q=l15 ---
        f32x4 St[4][2];
#pragma unroll
        for (int ktl = 0; ktl < 4; ktl++) {
            bf16x8 kf0 = *(const bf16x8*)&Ks[bb][(ktl * 16 + l15) * PADK + quad * 8];
            bf16x8 kf1 = *(const bf16x8*)&Ks[bb][(ktl * 16 + l15) * PADK + 32 + quad * 8];
#pragma unroll
            for (int qt = 0; qt < 2; qt++) {
                f32x4 acc = (f32x4)0.0f;
                acc = __builtin_amdgcn_mfma_f32_16x16x32_bf16(kf0, qf[qt][0], acc, 0, 0, 0);
                acc = __builtin_amdgcn_mfma_f32_16x16x32_bf16(kf1, qf[qt][1], acc, 0, 0, 0);
                St[ktl][qt] = acc;
            }
        }

        // --- scale+mask (log2 domain, one fma) then exp2 + partial sums ---
#pragma unroll
        for (int ktl = 0; ktl < 4; ktl++) {
            f32x4 ma = *(const f32x4*)&mads[kt * 64 + ktl * 16 + quad * 4];
#pragma unroll
            for (int qt = 0; qt < 2; qt++)
#pragma unroll
                for (int r = 0; r < 4; r++) {
                    float p = fexp2(St[ktl][qt][r] * SCL2 + ma[r]);
                    St[ktl][qt][r] = p;
                    sacc[qt][r] += p;
                }
        }

        // --- pack P^T to bf16 (already in B-frag layout for 16x16x16) ---
        bf16x4 pf[4][2];
#pragma unroll
        for (int ktl = 0; ktl < 4; ktl++)
#pragma unroll
            for (int qt = 0; qt < 2; qt++) {
                union { u32 u[2]; bf16x4 v; } pu;
                pu.u[0] = pack2(St[ktl][qt][0], St[ktl][qt][1]);
                pu.u[1] = pack2(St[ktl][qt][2], St[ktl][qt][3]);
                pf[ktl][qt] = pu.v;
            }

        // --- O^T += V^T P^T (16x16x16; A=V^T b64 reads from Vt) ---
#pragma unroll
        for (int ktl = 0; ktl < 4; ktl++)
#pragma unroll
            for (int dt = 0; dt < 4; dt++) {
                bf16x4 vf = *(const bf16x4*)&Vt[bb][(dt * 16 + l15) * PADV + ktl * 16 + quad * 4];
#pragma unroll
                for (int qt = 0; qt < 2; qt++)
                    O[dt][qt] = mfma16(vf, pf[ktl][qt], O[dt][qt]);
            }

        // --- write prefetched chunk into the other buffer ---
        if (kt < SEQ / 64 - 1) {
            u16* kd = &Ks[bb ^ 1][skey * PADK + sdk];
            *(bf16x8*)kd = nk0; *(bf16x8*)(kd + 8) = nk1;
#pragma unroll
            for (int i = 0; i < 8; i++)
                *(u32*)&Vt[bb ^ 1][(vd0 + i) * PADV + vkp2] = (u32)(u16)nv0[i] | ((u32)(u16)nv1[i] << 16);
        }
        __syncthreads();
    }

    // --- epilogue: single softmax-denominator reduction, normalize, write ---
    float inv[2];
#pragma unroll
    for (int qt = 0; qt < 2; qt++) {
        float s = (sacc[qt][0] + sacc[qt][1]) + (sacc[qt][2] + sacc[qt][3]);
        s += __shfl_xor(s, 16);
        s += __shfl_xor(s, 32);
        inv[qt] = 1.0f / s;
    }
#pragma unroll
    for (int qt = 0; qt < 2; qt++) {
        int q = qt0 * 128 + q0 + qt * 16 + l15;
        float* op = out + ((size_t)b * SEQ + q) * D_MODEL + h * DK;
#pragma unroll
        for (int dt = 0; dt < 4; dt++)
#pragma unroll
            for (int r = 0; r < 4; r++)
                op[dt * 16 + quad * 4 + r] = O[dt][qt][r] * inv[qt];
    }
}

extern "C" void kernel_launch(void* const* d_in, const int* in_sizes, int n_in,
                              void* d_out, int out_size, void* d_ws, size_t ws_size,
                              hipStream_t stream)
{
    const float* X  = (const float*)d_in[0];
    const int* mask = (const int*)d_in[1];
    const float* Wq = (const float*)d_in[2];
    const float* bq = (const float*)d_in[3];
    const float* Wk = (const float*)d_in[4];
    const float* bk = (const float*)d_in[5];
    const float* Wv = (const float*)d_in[6];
    const float* bv = (const float*)d_in[7];
    float* out = (float*)d_out;

    u16* Xb = (u16*)d_ws;
    u16* Wb = Xb + (size_t)MTOT * D_MODEL;
    u16* Qb = Wb + (size_t)3 * D_MODEL * D_MODEL;
    u16* Kb = Qb + (size_t)BATCH * NH * SEQ * DK;
    u16* Vb = Kb + (size_t)BATCH * NH * SEQ * DK;

    const int ncvt = (MTOT * D_MODEL + 3 * D_MODEL * D_MODEL) / 4;
    convert_bf16<<<(ncvt + 255) / 256, 256, 0, stream>>>(X, Wq, Wk, Wv, Xb, Wb);
    proj_mfma<<<dim3(MTOT / 128, D_MODEL / 128, 3), 256, 0, stream>>>(Xb, Wb, bq, bk, bv, Qb, Kb, Vb);
    attn_mfma<<<dim3(SEQ / 128, NH, BATCH), 256, 0, stream>>>(Qb, Kb, Vb, mask, out);
}